// Round 9
// baseline (198.011 us; speedup 1.0000x reference)
//
#include <hip/hip_runtime.h>
#include <hip/hip_bf16.h>
#include <stdint.h>

// Problem constants: x[16,256,64,64] f32; fc1[65,256]; fc2[1024,65]; fc2_b[1024];
// weight[4,256,256,3,3]; out[16,256,64,64] f32.

typedef __bf16 bf16x8 __attribute__((ext_vector_type(8)));
typedef float  f32x4  __attribute__((ext_vector_type(4)));

__device__ __forceinline__ unsigned short f2bf(float f) {
  union { float f; unsigned u; } v; v.f = f;
  return (unsigned short)((v.u + 0x7FFFu + ((v.u >> 16) & 1u)) >> 16);
}

__device__ __forceinline__ void gload16(const void* g, void* l) {
  __builtin_amdgcn_global_load_lds(
      (const __attribute__((address_space(1))) void*)g,
      (__attribute__((address_space(3))) void*)l, 16, 0, 0);
}

#define WAIT_VM(N) do { __builtin_amdgcn_sched_barrier(0); \
  asm volatile("s_waitcnt vmcnt(" #N ")" ::: "memory"); \
  __builtin_amdgcn_sched_barrier(0); } while (0)
#define BARRIER_PIN() do { __builtin_amdgcn_s_barrier(); \
  __builtin_amdgcn_sched_barrier(0); } while (0)
#define LGKM0_PIN() do { asm volatile("s_waitcnt lgkmcnt(0)" ::: "memory"); \
  __builtin_amdgcn_sched_barrier(0); } while (0)

// ---------------- Kernel A: pooling + NCHW f32 -> NHWC bf16 (r3 version) ----
// grid: 16 b * 4 cchunk * 64 y = 4096 blocks, 256 threads
__global__ __launch_bounds__(256) void k_prep(
    const float* __restrict__ x, unsigned short* __restrict__ xn,
    float* __restrict__ pooled_sum) {
  const int bx = blockIdx.x;
  const int y  = bx & 63;
  const int cc = (bx >> 6) & 3;
  const int b  = bx >> 8;
  const int t  = threadIdx.x;
  const int cl = t >> 2;
  const int q  = t & 3;
  const int xs = q * 16;

  const float4* s4 = (const float4*)(x + (((size_t)(b * 256 + cc * 64 + cl) * 64 + y) * 64 + xs));
  float v[16];
#pragma unroll
  for (int i = 0; i < 4; ++i) {
    float4 f = s4[i];
    v[i * 4 + 0] = f.x; v[i * 4 + 1] = f.y; v[i * 4 + 2] = f.z; v[i * 4 + 3] = f.w;
  }
  float s = 0.f;
#pragma unroll
  for (int i = 0; i < 16; ++i) s += v[i];
  s += __shfl_xor(s, 1);
  s += __shfl_xor(s, 2);
  if (q == 0) atomicAdd(&pooled_sum[b * 256 + cc * 64 + cl], s);

  __shared__ unsigned short tile[64][72];
#pragma unroll
  for (int j = 0; j < 16; ++j) tile[xs + j][cl] = f2bf(v[j]);
  __syncthreads();
  const int xp = t >> 2;
  const uint4* ls = (const uint4*)&tile[xp][q * 16];
  uint4 a0 = ls[0], a1 = ls[1];
  uint4* gd = (uint4*)(xn + ((size_t)((b * 64 + y) * 64 + xp) * 256 + cc * 64 + q * 16));
  gd[0] = a0; gd[1] = a1;
}

// ---------------- Kernel B1: fc1 -> relu -> fc2 -> softmax/T -> prob --------
__global__ __launch_bounds__(256) void k_fc(
    const float* __restrict__ pooled_sum,
    const float* __restrict__ fc1, const float* __restrict__ fc2,
    const float* __restrict__ fc2b, float* __restrict__ prob) {
  const int b = blockIdx.x, t = threadIdx.x;
  __shared__ float p[256];
  __shared__ float h[72];
  __shared__ float yv[1024];
  p[t] = pooled_sum[b * 256 + t] * (1.0f / 4096.0f);
  __syncthreads();
  if (t < 65) {
    float s = 0.f;
    for (int c = 0; c < 256; ++c) s += p[c] * fc1[t * 256 + c];
    h[t] = fmaxf(s, 0.f);
  }
  __syncthreads();
  for (int m = t; m < 1024; m += 256) {
    float s = fc2b[m];
    for (int j = 0; j < 65; ++j) s += h[j] * fc2[m * 65 + j];
    yv[m] = s;
  }
  __syncthreads();
  const float invT = 1.0f / 30.0f;
  float e0 = yv[t] * invT, e1 = yv[256 + t] * invT, e2 = yv[512 + t] * invT, e3 = yv[768 + t] * invT;
  float mx = fmaxf(fmaxf(e0, e1), fmaxf(e2, e3));
  float x0 = expf(e0 - mx), x1 = expf(e1 - mx), x2 = expf(e2 - mx), x3 = expf(e3 - mx);
  float r = 1.0f / (x0 + x1 + x2 + x3);
  prob[(b * 4 + 0) * 256 + t] = x0 * r;
  prob[(b * 4 + 1) * 256 + t] = x1 * r;
  prob[(b * 4 + 2) * 256 + t] = x2 * r;
  prob[(b * 4 + 3) * 256 + t] = x3 * r;
}

// ---------------- Kernel B2: aggT[b][tap][o][c] bf16 = sum_k prob*weight ----
__global__ __launch_bounds__(256) void k_agg(
    const float* __restrict__ weight, const float* __restrict__ prob,
    unsigned short* __restrict__ aggT) {
  const int o = blockIdx.x, t = threadIdx.x;
  __shared__ float w[4][2304];
#pragma unroll
  for (int k = 0; k < 4; ++k) {
    const float4* src = (const float4*)(weight + (size_t)(k * 256 + o) * 2304);
    float4* dst = (float4*)w[k];
    for (int j = t; j < 576; j += 256) dst[j] = src[j];
  }
  __syncthreads();
  const int c = t;
  float wv[4][9];
#pragma unroll
  for (int k = 0; k < 4; ++k)
#pragma unroll
    for (int tap = 0; tap < 9; ++tap) wv[k][tap] = w[k][c * 9 + tap];
  for (int b = 0; b < 16; ++b) {
    float p0 = prob[(b * 4 + 0) * 256 + o];
    float p1 = prob[(b * 4 + 1) * 256 + o];
    float p2 = prob[(b * 4 + 2) * 256 + o];
    float p3 = prob[(b * 4 + 3) * 256 + o];
#pragma unroll
    for (int tap = 0; tap < 9; ++tap) {
      float vv = p0 * wv[0][tap] + p1 * wv[1][tap] + p2 * wv[2][tap] + p3 * wv[3][tap];
      aggT[((size_t)(b * 9 + tap) * 256 + o) * 256 + c] = f2bf(vv);
    }
  }
}

// ---------------- Kernel C: per-sample implicit-GEMM conv, v9 ---------------
// v8's verified race-free pipeline, re-tiled for OCCUPANCY: 32-ch K-chunks.
//   X tile 256pos x 32ch = 16KB; W ring-3 of 128och x 32ch = 24KB -> LDS 40KB
//   -> 4 blocks/CU (vs 2). launch_bounds(256,4) caps VGPR 128 (frags: av[4]+
//   bv[4]+acc[16] = 96). 8 cc x 9 taps = 72 windows, 16 MFMA/wave each.
// 64B-row swizzle: 16B-slot = ((row>>1)&3) ^ lg; 8 distinct slots per 8-lane
// phase group -> conflict-free; staging source pre-swizzled (same involution).
// Counted vmcnt (2-load W, 4-load X): steady vm(2); tap8 vm(2) drains
// {W(g+1),X'}; cc7 tail vm(0). Sync skeleton identical to v8.
// grid: 16 b * 32 ytile * 2 otile = 1024 blocks, 256 threads
__global__ __launch_bounds__(256, 4) void k_conv(
    const unsigned short* __restrict__ xn,
    const unsigned short* __restrict__ aggT,
    const unsigned short* __restrict__ zpage,
    float* __restrict__ out) {
  const int bx0 = blockIdx.x;
  const int bx  = (bx0 & 7) * 128 + (bx0 >> 3);   // XCD swizzle: 2 samples/XCD
  const int ot = bx & 1;
  const int yt = (bx >> 1) & 31;
  const int b  = bx >> 6;
  const int y0 = yt * 2;
  const int o0 = ot * 128;
  const int t    = threadIdx.x;
  const int lane = t & 63;
  const int l15  = lane & 15;
  const int lg   = lane >> 4;
  const int wid  = t >> 6;
  const int wm   = wid >> 1;
  const int wn   = wid & 1;

  __shared__ unsigned short xbuf[256 * 32];      // 16 KiB
  __shared__ unsigned short wbuf[3][128 * 32];   // 3 x 8 KiB ring

  const f32x4 vzero = {0.f, 0.f, 0.f, 0.f};
  const bf16x8 bzero = {};
  f32x4 acc[4][4];
#pragma unroll
  for (int i = 0; i < 4; ++i)
#pragma unroll
    for (int j = 0; j < 4; ++j) acc[i][j] = vzero;

  const unsigned short* xb = xn + (size_t)b * (64 * 64 * 256);
  const unsigned short* ab = aggT + (size_t)b * (9 * 256 * 256) + (size_t)o0 * 256;

  // staging lambdas take only ints (no fragment pointers -> SROA-safe)
  auto stage_w = [&](int tap, int ccs) {        // 2 gload16 per thread
    unsigned short* dst = wbuf[tap % 3];
    const unsigned short* wsrc = ab + (size_t)tap * (256 * 256) + ccs * 32;
#pragma unroll
    for (int i = 0; i < 2; ++i) {
      int u = t + i * 256;                      // 512 units of 16B
      int o = u >> 2, s = u & 3;
      int j = s ^ ((o >> 1) & 3);               // pre-swizzled source slot
      gload16(wsrc + (size_t)o * 256 + j * 8, &dst[u * 8]);
    }
  };
  auto stage_x = [&](int ccs) {                 // 4 gload16 per thread
    const int c0s = ccs * 32;
#pragma unroll
    for (int i = 0; i < 4; ++i) {
      int u = t + i * 256;                      // 1024 units of 16B
      int pos = u >> 2, s = u & 3;
      int j = s ^ ((pos >> 1) & 3);
      int rr = pos >> 6, xc = pos & 63;
      int yy = y0 - 1 + rr;
      const unsigned short* src = (yy >= 0 && yy < 64)
          ? xb + ((size_t)yy * 64 + xc) * 256 + (c0s + j * 8)
          : zpage + ((u & 127) * 8);
      gload16(src, &xbuf[u * 8]);
    }
  };

// inline fragment-read macros (no pointer escape, all-literal indices)
#define READ_A1(MF, TAP) do {                                           \
    const int kh_ = (TAP) / 3, d_ = (TAP) % 3 - 1;                      \
    int xsrc_ = (MF) * 16 + l15 + d_;                                   \
    bool valid_ = (xsrc_ >= 0) && (xsrc_ < 64);                         \
    int pos_ = (wm + kh_) * 64 + min(max(xsrc_, 0), 63);                \
    int su_ = ((pos_ >> 1) & 3) ^ lg;                                   \
    bf16x8 v_ = *(const bf16x8*)&xbuf[pos_ * 32 + su_ * 8];             \
    av[MF] = valid_ ? v_ : bzero;                                       \
  } while (0)
#define READ_A_ALL(TAP) do {                                            \
    READ_A1(0, TAP); READ_A1(1, TAP); READ_A1(2, TAP); READ_A1(3, TAP); \
  } while (0)
#define READ_B1(NF, SLOT) do {                                          \
    int oo_ = wn * 64 + (NF) * 16 + l15;                                \
    int su_ = ((oo_ >> 1) & 3) ^ lg;                                    \
    bv[NF] = *(const bf16x8*)&wbuf[SLOT][oo_ * 32 + su_ * 8];           \
  } while (0)
#define READ_B_ALL(SLOT) do {                                           \
    READ_B1(0, SLOT); READ_B1(1, SLOT); READ_B1(2, SLOT); READ_B1(3, SLOT); \
  } while (0)
#define MFMA_ALL() do {                                                 \
    __builtin_amdgcn_s_setprio(1);                                      \
    acc[0][0] = __builtin_amdgcn_mfma_f32_16x16x32_bf16(av[0], bv[0], acc[0][0], 0, 0, 0); \
    acc[0][1] = __builtin_amdgcn_mfma_f32_16x16x32_bf16(av[0], bv[1], acc[0][1], 0, 0, 0); \
    acc[0][2] = __builtin_amdgcn_mfma_f32_16x16x32_bf16(av[0], bv[2], acc[0][2], 0, 0, 0); \
    acc[0][3] = __builtin_amdgcn_mfma_f32_16x16x32_bf16(av[0], bv[3], acc[0][3], 0, 0, 0); \
    acc[1][0] = __builtin_amdgcn_mfma_f32_16x16x32_bf16(av[1], bv[0], acc[1][0], 0, 0, 0); \
    acc[1][1] = __builtin_amdgcn_mfma_f32_16x16x32_bf16(av[1], bv[1], acc[1][1], 0, 0, 0); \
    acc[1][2] = __builtin_amdgcn_mfma_f32_16x16x32_bf16(av[1], bv[2], acc[1][2], 0, 0, 0); \
    acc[1][3] = __builtin_amdgcn_mfma_f32_16x16x32_bf16(av[1], bv[3], acc[1][3], 0, 0, 0); \
    acc[2][0] = __builtin_amdgcn_mfma_f32_16x16x32_bf16(av[2], bv[0], acc[2][0], 0, 0, 0); \
    acc[2][1] = __builtin_amdgcn_mfma_f32_16x16x32_bf16(av[2], bv[1], acc[2][1], 0, 0, 0); \
    acc[2][2] = __builtin_amdgcn_mfma_f32_16x16x32_bf16(av[2], bv[2], acc[2][2], 0, 0, 0); \
    acc[2][3] = __builtin_amdgcn_mfma_f32_16x16x32_bf16(av[2], bv[3], acc[2][3], 0, 0, 0); \
    acc[3][0] = __builtin_amdgcn_mfma_f32_16x16x32_bf16(av[3], bv[0], acc[3][0], 0, 0, 0); \
    acc[3][1] = __builtin_amdgcn_mfma_f32_16x16x32_bf16(av[3], bv[1], acc[3][1], 0, 0, 0); \
    acc[3][2] = __builtin_amdgcn_mfma_f32_16x16x32_bf16(av[3], bv[2], acc[3][2], 0, 0, 0); \
    acc[3][3] = __builtin_amdgcn_mfma_f32_16x16x32_bf16(av[3], bv[3], acc[3][3], 0, 0, 0); \
    __builtin_amdgcn_s_setprio(0);                                      \
  } while (0)

  bf16x8 av[4], bv[4];   // fragments for the CURRENT tap (read last phase)

  // prologue: X(0)[4] + W(0)->slot0 [2] + W(1)->slot1 [2]
  stage_x(0);
  stage_w(0, 0);
  stage_w(1, 0);
  WAIT_VM(2);            // X + W0 landed; W1 (2 loads) in flight
  BARRIER_PIN();
  READ_B_ALL(0);
  READ_A_ALL(0);

  for (int cc = 0; cc < 8; ++cc) {
#pragma unroll
    for (int tap = 0; tap < 9; ++tap) {
      // --- stage next tiles (tap8: xbuf is clean -- retired at tap7-end) ---
      if (tap == 8 && cc < 7) stage_x(cc + 1);
      if (cc < 7 || tap <= 6) stage_w((tap + 2) % 9, cc + (tap + 2) / 9);

      // --- MFMA(tap): registers only ---
      MFMA_ALL();

      // --- end-of-phase: sync + read fragments for tap+1 ---
      if (tap < 7) {
        READ_A_ALL(tap + 1);    // pre-vm: xbuf stable; overlaps MFMA drain
        WAIT_VM(2);             // drains W(g+1); keeps W(g+2)
        BARRIER_PIN();
        READ_B_ALL((tap + 1) % 3);
      } else if (tap == 7) {
        READ_A_ALL(8);          // current xbuf, pre-vm
        if (cc < 7) { WAIT_VM(2); } else { WAIT_VM(0); }
        BARRIER_PIN();
        READ_B_ALL(2);          // slot 8%3
        if (cc < 7) {           // retire ALL waves' xbuf reads before tap8's
          LGKM0_PIN();          // stage_x can overwrite xbuf
          BARRIER_PIN();
        }
      } else {                  // tap == 8
        if (cc < 7) {
          WAIT_VM(2);           // drains {W(g+1), X'}; keeps W(g+2)
          BARRIER_PIN();
          READ_B_ALL(0);        // slot 9%3 -> next cc tap0
          READ_A_ALL(0);        // new xbuf (landed)
        }                       // cc==7: fall through to epilogue
      }
    }
  }
#undef READ_A1
#undef READ_A_ALL
#undef READ_B1
#undef READ_B_ALL
#undef MFMA_ALL

  // epilogue: D row = pixel = (lane>>4)*4 + reg, col = ochan = lane&15
  const int yrow = y0 + wm;
#pragma unroll
  for (int nf = 0; nf < 4; ++nf) {
    int och = o0 + wn * 64 + nf * 16 + l15;
    float* op = out + ((size_t)(b * 256 + och) * 4096) + yrow * 64;
#pragma unroll
    for (int mf = 0; mf < 4; ++mf) {
      int xcb = mf * 16 + lg * 4;
      *(float4*)(op + xcb) = *(float4*)&acc[mf][nf];
    }
  }
}

extern "C" void kernel_launch(void* const* d_in, const int* in_sizes, int n_in,
                              void* d_out, int out_size, void* d_ws, size_t ws_size,
                              hipStream_t stream) {
  (void)in_sizes; (void)n_in; (void)out_size; (void)ws_size;
  const float* x      = (const float*)d_in[0];
  const float* fc1    = (const float*)d_in[1];
  const float* fc2    = (const float*)d_in[2];
  const float* fc2b   = (const float*)d_in[3];
  const float* weight = (const float*)d_in[4];
  float* out = (float*)d_out;

  // workspace layout (~52.7 MB):
  //   [0,4K)            zero page (row-halo source for global_load_lds)
  //   [4K,20K)          pooled_sum f32[16][256]
  //   [20K, 86016)      prob f32[16][4][256]
  //   [131072, +18.87MB)  aggT bf16[16][9][256][256]
  //   [19,005,440, +33.55MB) x_nhwc bf16[16][64][64][256]
  char* ws = (char*)d_ws;
  unsigned short* zpage  = (unsigned short*)ws;
  float*          pooled = (float*)(ws + 4096);
  float*          prob   = (float*)(ws + 20480);
  unsigned short* aggT   = (unsigned short*)(ws + 131072);
  unsigned short* xnhwc  = (unsigned short*)(ws + 131072 + 18874368);

  hipMemsetAsync(d_ws, 0, 20480, stream);  // zero page + pooled_sum, every launch
  k_prep<<<dim3(16 * 4 * 64), dim3(256), 0, stream>>>(x, xnhwc, pooled);
  k_fc  <<<dim3(16),          dim3(256), 0, stream>>>(pooled, fc1, fc2, fc2b, prob);
  k_agg <<<dim3(256),         dim3(256), 0, stream>>>(weight, prob, aggT);
  k_conv<<<dim3(1024),        dim3(256), 0, stream>>>(xnhwc, aggT, zpage, out);
}

// Round 10
// 135.934 us; speedup vs baseline: 1.4567x; 1.4567x over previous
//
#include <hip/hip_runtime.h>
#include <hip/hip_bf16.h>
#include <stdint.h>

// Problem constants: x[16,256,64,64] f32; fc1[65,256]; fc2[1024,65]; fc2_b[1024];
// weight[4,256,256,3,3]; out[16,256,64,64] f32.

typedef __bf16 bf16x8 __attribute__((ext_vector_type(8)));
typedef float  f32x4  __attribute__((ext_vector_type(4)));

__device__ __forceinline__ unsigned short f2bf(float f) {
  union { float f; unsigned u; } v; v.f = f;
  return (unsigned short)((v.u + 0x7FFFu + ((v.u >> 16) & 1u)) >> 16);
}

__device__ __forceinline__ void gload16(const void* g, void* l) {
  __builtin_amdgcn_global_load_lds(
      (const __attribute__((address_space(1))) void*)g,
      (__attribute__((address_space(3))) void*)l, 16, 0, 0);
}

#define WAIT_VM(N) do { __builtin_amdgcn_sched_barrier(0); \
  asm volatile("s_waitcnt vmcnt(" #N ")" ::: "memory"); \
  __builtin_amdgcn_sched_barrier(0); } while (0)
#define BARRIER_PIN() do { __builtin_amdgcn_s_barrier(); \
  __builtin_amdgcn_sched_barrier(0); } while (0)
#define LGKM0_PIN() do { asm volatile("s_waitcnt lgkmcnt(0)" ::: "memory"); \
  __builtin_amdgcn_sched_barrier(0); } while (0)

// ---------------- Kernel A: pooling + NCHW f32 -> NHWC bf16 (r3 version) ----
// grid: 16 b * 4 cchunk * 64 y = 4096 blocks, 256 threads
__global__ __launch_bounds__(256) void k_prep(
    const float* __restrict__ x, unsigned short* __restrict__ xn,
    float* __restrict__ pooled_sum) {
  const int bx = blockIdx.x;
  const int y  = bx & 63;
  const int cc = (bx >> 6) & 3;
  const int b  = bx >> 8;
  const int t  = threadIdx.x;
  const int cl = t >> 2;
  const int q  = t & 3;
  const int xs = q * 16;

  const float4* s4 = (const float4*)(x + (((size_t)(b * 256 + cc * 64 + cl) * 64 + y) * 64 + xs));
  float v[16];
#pragma unroll
  for (int i = 0; i < 4; ++i) {
    float4 f = s4[i];
    v[i * 4 + 0] = f.x; v[i * 4 + 1] = f.y; v[i * 4 + 2] = f.z; v[i * 4 + 3] = f.w;
  }
  float s = 0.f;
#pragma unroll
  for (int i = 0; i < 16; ++i) s += v[i];
  s += __shfl_xor(s, 1);
  s += __shfl_xor(s, 2);
  if (q == 0) atomicAdd(&pooled_sum[b * 256 + cc * 64 + cl], s);

  __shared__ unsigned short tile[64][72];
#pragma unroll
  for (int j = 0; j < 16; ++j) tile[xs + j][cl] = f2bf(v[j]);
  __syncthreads();
  const int xp = t >> 2;
  const uint4* ls = (const uint4*)&tile[xp][q * 16];
  uint4 a0 = ls[0], a1 = ls[1];
  uint4* gd = (uint4*)(xn + ((size_t)((b * 64 + y) * 64 + xp) * 256 + cc * 64 + q * 16));
  gd[0] = a0; gd[1] = a1;
}

// ---------------- Kernel B1: fc1 -> relu -> fc2 -> softmax/T -> prob --------
__global__ __launch_bounds__(256) void k_fc(
    const float* __restrict__ pooled_sum,
    const float* __restrict__ fc1, const float* __restrict__ fc2,
    const float* __restrict__ fc2b, float* __restrict__ prob) {
  const int b = blockIdx.x, t = threadIdx.x;
  __shared__ float p[256];
  __shared__ float h[72];
  __shared__ float yv[1024];
  p[t] = pooled_sum[b * 256 + t] * (1.0f / 4096.0f);
  __syncthreads();
  if (t < 65) {
    float s = 0.f;
    for (int c = 0; c < 256; ++c) s += p[c] * fc1[t * 256 + c];
    h[t] = fmaxf(s, 0.f);
  }
  __syncthreads();
  for (int m = t; m < 1024; m += 256) {
    float s = fc2b[m];
    for (int j = 0; j < 65; ++j) s += h[j] * fc2[m * 65 + j];
    yv[m] = s;
  }
  __syncthreads();
  const float invT = 1.0f / 30.0f;
  float e0 = yv[t] * invT, e1 = yv[256 + t] * invT, e2 = yv[512 + t] * invT, e3 = yv[768 + t] * invT;
  float mx = fmaxf(fmaxf(e0, e1), fmaxf(e2, e3));
  float x0 = expf(e0 - mx), x1 = expf(e1 - mx), x2 = expf(e2 - mx), x3 = expf(e3 - mx);
  float r = 1.0f / (x0 + x1 + x2 + x3);
  prob[(b * 4 + 0) * 256 + t] = x0 * r;
  prob[(b * 4 + 1) * 256 + t] = x1 * r;
  prob[(b * 4 + 2) * 256 + t] = x2 * r;
  prob[(b * 4 + 3) * 256 + t] = x3 * r;
}

// ---------------- Kernel B2: aggT[b][tap][o][c] bf16 = sum_k prob*weight ----
__global__ __launch_bounds__(256) void k_agg(
    const float* __restrict__ weight, const float* __restrict__ prob,
    unsigned short* __restrict__ aggT) {
  const int o = blockIdx.x, t = threadIdx.x;
  __shared__ float w[4][2304];
#pragma unroll
  for (int k = 0; k < 4; ++k) {
    const float4* src = (const float4*)(weight + (size_t)(k * 256 + o) * 2304);
    float4* dst = (float4*)w[k];
    for (int j = t; j < 576; j += 256) dst[j] = src[j];
  }
  __syncthreads();
  const int c = t;
  float wv[4][9];
#pragma unroll
  for (int k = 0; k < 4; ++k)
#pragma unroll
    for (int tap = 0; tap < 9; ++tap) wv[k][tap] = w[k][c * 9 + tap];
  for (int b = 0; b < 16; ++b) {
    float p0 = prob[(b * 4 + 0) * 256 + o];
    float p1 = prob[(b * 4 + 1) * 256 + o];
    float p2 = prob[(b * 4 + 2) * 256 + o];
    float p3 = prob[(b * 4 + 3) * 256 + o];
#pragma unroll
    for (int tap = 0; tap < 9; ++tap) {
      float vv = p0 * wv[0][tap] + p1 * wv[1][tap] + p2 * wv[2][tap] + p3 * wv[3][tap];
      aggT[((size_t)(b * 9 + tap) * 256 + o) * 256 + c] = f2bf(vv);
    }
  }
}

// ---------------- Kernel C: per-sample implicit-GEMM conv, v10 --------------
// v9 tiling (32-ch K-chunks: X 16KB + W ring-3 24KB = 40KB LDS -> 4 blocks/CU)
// with the launch-bounds fix: empirically this toolchain caps VGPR at 256/N
// for the second arg; (256,4) gave 64 VGPR -> catastrophic spill (r9).
// (256,2) -> cap 128; v9's register need (~105-120: av[4]+bv[4]=32, acc=64,
// addressing) fits -> no spill, occupancy LDS-bound at 4 blocks/CU.
// Pipeline/sync skeleton = v8's verified race-free one (A-reads pre-vm,
// B-reads post-barrier, tap7-end lgkm0+barrier before X republish).
// Counted vmcnt (2-load W, 4-load X): steady vm(2); tap8 vm(2); cc7 vm(0).
// grid: 16 b * 32 ytile * 2 otile = 1024 blocks, 256 threads
__global__ __launch_bounds__(256, 2) void k_conv(
    const unsigned short* __restrict__ xn,
    const unsigned short* __restrict__ aggT,
    const unsigned short* __restrict__ zpage,
    float* __restrict__ out) {
  const int bx0 = blockIdx.x;
  const int bx  = (bx0 & 7) * 128 + (bx0 >> 3);   // XCD swizzle: 2 samples/XCD
  const int ot = bx & 1;
  const int yt = (bx >> 1) & 31;
  const int b  = bx >> 6;
  const int y0 = yt * 2;
  const int o0 = ot * 128;
  const int t    = threadIdx.x;
  const int lane = t & 63;
  const int l15  = lane & 15;
  const int lg   = lane >> 4;
  const int wid  = t >> 6;
  const int wm   = wid >> 1;
  const int wn   = wid & 1;

  __shared__ unsigned short xbuf[256 * 32];      // 16 KiB
  __shared__ unsigned short wbuf[3][128 * 32];   // 3 x 8 KiB ring

  const f32x4 vzero = {0.f, 0.f, 0.f, 0.f};
  const bf16x8 bzero = {};
  f32x4 acc[4][4];
#pragma unroll
  for (int i = 0; i < 4; ++i)
#pragma unroll
    for (int j = 0; j < 4; ++j) acc[i][j] = vzero;

  const unsigned short* xb = xn + (size_t)b * (64 * 64 * 256);
  const unsigned short* ab = aggT + (size_t)b * (9 * 256 * 256) + (size_t)o0 * 256;

  // staging lambdas take only ints (no fragment pointers -> SROA-safe)
  auto stage_w = [&](int tap, int ccs) {        // 2 gload16 per thread
    unsigned short* dst = wbuf[tap % 3];
    const unsigned short* wsrc = ab + (size_t)tap * (256 * 256) + ccs * 32;
#pragma unroll
    for (int i = 0; i < 2; ++i) {
      int u = t + i * 256;                      // 512 units of 16B
      int o = u >> 2, s = u & 3;
      int j = s ^ ((o >> 1) & 3);               // pre-swizzled source slot
      gload16(wsrc + (size_t)o * 256 + j * 8, &dst[u * 8]);
    }
  };
  auto stage_x = [&](int ccs) {                 // 4 gload16 per thread
    const int c0s = ccs * 32;
#pragma unroll
    for (int i = 0; i < 4; ++i) {
      int u = t + i * 256;                      // 1024 units of 16B
      int pos = u >> 2, s = u & 3;
      int j = s ^ ((pos >> 1) & 3);
      int rr = pos >> 6, xc = pos & 63;
      int yy = y0 - 1 + rr;
      const unsigned short* src = (yy >= 0 && yy < 64)
          ? xb + ((size_t)yy * 64 + xc) * 256 + (c0s + j * 8)
          : zpage + ((u & 127) * 8);
      gload16(src, &xbuf[u * 8]);
    }
  };

// inline fragment-read macros (no pointer escape, all-literal indices)
#define READ_A1(MF, TAP) do {                                           \
    const int kh_ = (TAP) / 3, d_ = (TAP) % 3 - 1;                      \
    int xsrc_ = (MF) * 16 + l15 + d_;                                   \
    bool valid_ = (xsrc_ >= 0) && (xsrc_ < 64);                         \
    int pos_ = (wm + kh_) * 64 + min(max(xsrc_, 0), 63);                \
    int su_ = ((pos_ >> 1) & 3) ^ lg;                                   \
    bf16x8 v_ = *(const bf16x8*)&xbuf[pos_ * 32 + su_ * 8];             \
    av[MF] = valid_ ? v_ : bzero;                                       \
  } while (0)
#define READ_A_ALL(TAP) do {                                            \
    READ_A1(0, TAP); READ_A1(1, TAP); READ_A1(2, TAP); READ_A1(3, TAP); \
  } while (0)
#define READ_B1(NF, SLOT) do {                                          \
    int oo_ = wn * 64 + (NF) * 16 + l15;                                \
    int su_ = ((oo_ >> 1) & 3) ^ lg;                                    \
    bv[NF] = *(const bf16x8*)&wbuf[SLOT][oo_ * 32 + su_ * 8];           \
  } while (0)
#define READ_B_ALL(SLOT) do {                                           \
    READ_B1(0, SLOT); READ_B1(1, SLOT); READ_B1(2, SLOT); READ_B1(3, SLOT); \
  } while (0)
#define MFMA_ALL() do {                                                 \
    __builtin_amdgcn_s_setprio(1);                                      \
    acc[0][0] = __builtin_amdgcn_mfma_f32_16x16x32_bf16(av[0], bv[0], acc[0][0], 0, 0, 0); \
    acc[0][1] = __builtin_amdgcn_mfma_f32_16x16x32_bf16(av[0], bv[1], acc[0][1], 0, 0, 0); \
    acc[0][2] = __builtin_amdgcn_mfma_f32_16x16x32_bf16(av[0], bv[2], acc[0][2], 0, 0, 0); \
    acc[0][3] = __builtin_amdgcn_mfma_f32_16x16x32_bf16(av[0], bv[3], acc[0][3], 0, 0, 0); \
    acc[1][0] = __builtin_amdgcn_mfma_f32_16x16x32_bf16(av[1], bv[0], acc[1][0], 0, 0, 0); \
    acc[1][1] = __builtin_amdgcn_mfma_f32_16x16x32_bf16(av[1], bv[1], acc[1][1], 0, 0, 0); \
    acc[1][2] = __builtin_amdgcn_mfma_f32_16x16x32_bf16(av[1], bv[2], acc[1][2], 0, 0, 0); \
    acc[1][3] = __builtin_amdgcn_mfma_f32_16x16x32_bf16(av[1], bv[3], acc[1][3], 0, 0, 0); \
    acc[2][0] = __builtin_amdgcn_mfma_f32_16x16x32_bf16(av[2], bv[0], acc[2][0], 0, 0, 0); \
    acc[2][1] = __builtin_amdgcn_mfma_f32_16x16x32_bf16(av[2], bv[1], acc[2][1], 0, 0, 0); \
    acc[2][2] = __builtin_amdgcn_mfma_f32_16x16x32_bf16(av[2], bv[2], acc[2][2], 0, 0, 0); \
    acc[2][3] = __builtin_amdgcn_mfma_f32_16x16x32_bf16(av[2], bv[3], acc[2][3], 0, 0, 0); \
    acc[3][0] = __builtin_amdgcn_mfma_f32_16x16x32_bf16(av[3], bv[0], acc[3][0], 0, 0, 0); \
    acc[3][1] = __builtin_amdgcn_mfma_f32_16x16x32_bf16(av[3], bv[1], acc[3][1], 0, 0, 0); \
    acc[3][2] = __builtin_amdgcn_mfma_f32_16x16x32_bf16(av[3], bv[2], acc[3][2], 0, 0, 0); \
    acc[3][3] = __builtin_amdgcn_mfma_f32_16x16x32_bf16(av[3], bv[3], acc[3][3], 0, 0, 0); \
    __builtin_amdgcn_s_setprio(0);                                      \
  } while (0)

  bf16x8 av[4], bv[4];   // fragments for the CURRENT tap (read last phase)

  // prologue: X(0)[4] + W(0)->slot0 [2] + W(1)->slot1 [2]
  stage_x(0);
  stage_w(0, 0);
  stage_w(1, 0);
  WAIT_VM(2);            // X + W0 landed; W1 (2 loads) in flight
  BARRIER_PIN();
  READ_B_ALL(0);
  READ_A_ALL(0);

  for (int cc = 0; cc < 8; ++cc) {
#pragma unroll
    for (int tap = 0; tap < 9; ++tap) {
      // --- stage next tiles (tap8: xbuf is clean -- retired at tap7-end) ---
      if (tap == 8 && cc < 7) stage_x(cc + 1);
      if (cc < 7 || tap <= 6) stage_w((tap + 2) % 9, cc + (tap + 2) / 9);

      // --- MFMA(tap): registers only ---
      MFMA_ALL();

      // --- end-of-phase: sync + read fragments for tap+1 ---
      if (tap < 7) {
        READ_A_ALL(tap + 1);    // pre-vm: xbuf stable; overlaps MFMA drain
        WAIT_VM(2);             // drains W(g+1); keeps W(g+2)
        BARRIER_PIN();
        READ_B_ALL((tap + 1) % 3);
      } else if (tap == 7) {
        READ_A_ALL(8);          // current xbuf, pre-vm
        if (cc < 7) { WAIT_VM(2); } else { WAIT_VM(0); }
        BARRIER_PIN();
        READ_B_ALL(2);          // slot 8%3
        if (cc < 7) {           // retire ALL waves' xbuf reads before tap8's
          LGKM0_PIN();          // stage_x can overwrite xbuf
          BARRIER_PIN();
        }
      } else {                  // tap == 8
        if (cc < 7) {
          WAIT_VM(2);           // drains {W(g+1), X'}; keeps W(g+2)
          BARRIER_PIN();
          READ_B_ALL(0);        // slot 9%3 -> next cc tap0
          READ_A_ALL(0);        // new xbuf (landed)
        }                       // cc==7: fall through to epilogue
      }
    }
  }
#undef READ_A1
#undef READ_A_ALL
#undef READ_B1
#undef READ_B_ALL
#undef MFMA_ALL

  // epilogue: D row = pixel = (lane>>4)*4 + reg, col = ochan = lane&15
  const int yrow = y0 + wm;
#pragma unroll
  for (int nf = 0; nf < 4; ++nf) {
    int och = o0 + wn * 64 + nf * 16 + l15;
    float* op = out + ((size_t)(b * 256 + och) * 4096) + yrow * 64;
#pragma unroll
    for (int mf = 0; mf < 4; ++mf) {
      int xcb = mf * 16 + lg * 4;
      *(float4*)(op + xcb) = *(float4*)&acc[mf][nf];
    }
  }
}

extern "C" void kernel_launch(void* const* d_in, const int* in_sizes, int n_in,
                              void* d_out, int out_size, void* d_ws, size_t ws_size,
                              hipStream_t stream) {
  (void)in_sizes; (void)n_in; (void)out_size; (void)ws_size;
  const float* x      = (const float*)d_in[0];
  const float* fc1    = (const float*)d_in[1];
  const float* fc2    = (const float*)d_in[2];
  const float* fc2b   = (const float*)d_in[3];
  const float* weight = (const float*)d_in[4];
  float* out = (float*)d_out;

  // workspace layout (~52.7 MB):
  //   [0,4K)            zero page (row-halo source for global_load_lds)
  //   [4K,20K)          pooled_sum f32[16][256]
  //   [20K, 86016)      prob f32[16][4][256]
  //   [131072, +18.87MB)  aggT bf16[16][9][256][256]
  //   [19,005,440, +33.55MB) x_nhwc bf16[16][64][64][256]
  char* ws = (char*)d_ws;
  unsigned short* zpage  = (unsigned short*)ws;
  float*          pooled = (float*)(ws + 4096);
  float*          prob   = (float*)(ws + 20480);
  unsigned short* aggT   = (unsigned short*)(ws + 131072);
  unsigned short* xnhwc  = (unsigned short*)(ws + 131072 + 18874368);

  hipMemsetAsync(d_ws, 0, 20480, stream);  // zero page + pooled_sum, every launch
  k_prep<<<dim3(16 * 4 * 64), dim3(256), 0, stream>>>(x, xnhwc, pooled);
  k_fc  <<<dim3(16),          dim3(256), 0, stream>>>(pooled, fc1, fc2, fc2b, prob);
  k_agg <<<dim3(256),         dim3(256), 0, stream>>>(weight, prob, aggT);
  k_conv<<<dim3(1024),        dim3(256), 0, stream>>>(xnhwc, aggT, zpage, out);
}